// Round 4
// baseline (201.045 us; speedup 1.0000x reference)
//
#include <hip/hip_runtime.h>
#include <hip/hip_bf16.h>

#define N_NODES 50000
#define HDIM    256
#define CDIM    32
#define JDIM    96   // C*3 output elements per node
#define NB      32   // nodes per block
#define NTY     16   // j-groups of 6 outputs each (16*6 == 96)
#define BPAD    8    // floats per (h,ty) cell: 6 used + 2 pad -> 32B, 16B-aligned

// Precomputed B[h][ty][8]: B[h, ty*6+e] = W2[h,c]*W1[k,h], j=ty*6+e, c=j/3, k=j%3.
// 256*16*8*4 = 128 KiB; L2-resident; rebuilt every launch (idempotent).
__device__ float g_B[HDIM * NTY * BPAD];

template<bool ISBF>
__device__ __forceinline__ float ldv(const void* __restrict__ p, int i) {
    if constexpr (ISBF) return __bfloat162float(((const __hip_bfloat16*)p)[i]);
    else                return ((const float*)p)[i];
}

// Runtime dtype detection (wave-uniform): bf16 ~N(0,1) has exponent in [100,140].
__device__ __forceinline__ bool detect_bf(const void* pos) {
    unsigned short uw = ((const unsigned short*)pos)[threadIdx.x & 63];
    int ef = (uw >> 7) & 0xFF;
    unsigned long long bal = __ballot(ef >= 100 && ef <= 140);
    return __popcll(bal) >= 56;
}

template<bool ISBF>
__device__ __forceinline__ void build_impl(const void* __restrict__ W1,
                                           const void* __restrict__ W2) {
    const int e   = blockIdx.x * 256 + threadIdx.x;  // 0..32767
    const int sub = e & 7;
    const int ty  = (e >> 3) & 15;
    const int h   = e >> 7;
    float v = 0.0f;
    if (sub < 6) {
        const int j = ty * 6 + sub;
        v = ldv<ISBF>(W1, (j % 3) * HDIM + h) * ldv<ISBF>(W2, h * CDIM + j / 3);
    }
    g_B[e] = v;
}

__global__ __launch_bounds__(256) void build_B(const void* __restrict__ pos,
                                               const void* __restrict__ W1,
                                               const void* __restrict__ W2) {
    if (detect_bf(pos)) build_impl<true >(W1, W2);
    else                build_impl<false>(W1, W2);
}

// Main: out[n,j] = sum_h S[n,h] * B[h,j], S = sech^2(pos.W1 + b1).
// Block 256 = 4 waves. Phase 1: fill S[256][32] in LDS (one barrier).
// Phase 2: thread (tx,ty) owns nodes {2tx,2tx+1} x j in [6ty,6ty+6):
//   per h: 1 ds_read_b64 (S) + dwordx4+dwordx2 (B, vmcnt) + 12 FMAs, imm offsets.
// No SMEM ops in the loop -> lgkmcnt counts DS only, vmcnt counts B loads:
// both precisely countable -> compiler software-pipelines cleanly.
template<bool ISBF>
__device__ __forceinline__ void run_impl(
    const void* __restrict__ pos,
    const void* __restrict__ W1,
    const void* __restrict__ b1,
    void* __restrict__ out,
    float (*S)[NB])
{
    const int tid = threadIdx.x;

    // ---- phase 1: S[h][nl] = sech^2(z); thread = (h-group, node) ----
    {
        const int nl = tid & 31;         // node within block
        const int hg = tid >> 5;         // 0..7, 32 h-values each
        const int n  = blockIdx.x * NB + nl;
        float p0 = 0.f, p1 = 0.f, p2 = 0.f;
        if (n < N_NODES) {
            p0 = ldv<ISBF>(pos, n * 3 + 0);
            p1 = ldv<ISBF>(pos, n * 3 + 1);
            p2 = ldv<ISBF>(pos, n * 3 + 2);
        }
#pragma unroll 8
        for (int i = 0; i < 32; ++i) {
            const int h = hg * 32 + i;
            float zb = ldv<ISBF>(b1, h);
            float wx = ldv<ISBF>(W1, 0 * HDIM + h);
            float wy = ldv<ISBF>(W1, 1 * HDIM + h);
            float wz = ldv<ISBF>(W1, 2 * HDIM + h);
            float z  = fmaf(p0, wx, fmaf(p1, wy, fmaf(p2, wz, zb)));
            // sech^2(z) = 4u/(1+u)^2, u = e^{-2|z|}: branch-free, no overflow
            float u   = __expf(-2.0f * fabsf(z));
            float inv = __builtin_amdgcn_rcpf(1.0f + u);
            S[h][nl] = 4.0f * u * inv * inv;   // 2-way bank alias = free
        }
    }
    __syncthreads();

    // ---- phase 2: register-tiled GEMM ----
    const int tx = tid & 15;             // node pair: n0 = 2*tx
    const int ty = tid >> 4;             // j-group: j0 = 6*ty
    const int n0 = blockIdx.x * NB + tx * 2;

    float acc[12];                        // acc[e*2+d] = out[n0+d][6ty+e]
#pragma unroll
    for (int j = 0; j < 12; ++j) acc[j] = 0.0f;

    const float* __restrict__ Bp = g_B + ty * BPAD;   // + h*128 floats per row
    const float* __restrict__ Sp = &S[0][tx * 2];     // + h*32 floats per row

    for (int g = 0; g < 8; ++g) {
#pragma unroll
        for (int i = 0; i < 32; ++i) {
            const int h = g * 32 + i;
            const float2 s2 = *(const float2*)(Sp + h * NB);          // ds_read_b64
            const float4 b0 = *(const float4*)(Bp + h * NTY * BPAD);      // dwordx4
            const float2 b4 = *(const float2*)(Bp + h * NTY * BPAD + 4);  // dwordx2
            acc[0]  = fmaf(s2.x, b0.x, acc[0]);
            acc[1]  = fmaf(s2.y, b0.x, acc[1]);
            acc[2]  = fmaf(s2.x, b0.y, acc[2]);
            acc[3]  = fmaf(s2.y, b0.y, acc[3]);
            acc[4]  = fmaf(s2.x, b0.z, acc[4]);
            acc[5]  = fmaf(s2.y, b0.z, acc[5]);
            acc[6]  = fmaf(s2.x, b0.w, acc[6]);
            acc[7]  = fmaf(s2.y, b0.w, acc[7]);
            acc[8]  = fmaf(s2.x, b4.x, acc[8]);
            acc[9]  = fmaf(s2.y, b4.x, acc[9]);
            acc[10] = fmaf(s2.x, b4.y, acc[10]);
            acc[11] = fmaf(s2.y, b4.y, acc[11]);
        }
    }

    // ---- store: 6 outputs per owned node ----
#pragma unroll
    for (int d = 0; d < 2; ++d) {
        const int n = n0 + d;
        if (n >= N_NODES) continue;
        if constexpr (ISBF) {
            unsigned int* op = (unsigned int*)((__hip_bfloat16*)out + (size_t)n * JDIM + ty * 6);
#pragma unroll
            for (int e = 0; e < 6; e += 2) {
                unsigned short lo = __hip_bfloat16_raw(__float2bfloat16(acc[(e + 0) * 2 + d])).x;
                unsigned short hi = __hip_bfloat16_raw(__float2bfloat16(acc[(e + 1) * 2 + d])).x;
                op[e >> 1] = ((unsigned int)hi << 16) | lo;   // 4B-aligned
            }
        } else {
            float2* op = (float2*)((float*)out + (size_t)n * JDIM + ty * 6);  // 8B-aligned
#pragma unroll
            for (int e = 0; e < 6; e += 2)
                op[e >> 1] = make_float2(acc[(e + 0) * 2 + d], acc[(e + 1) * 2 + d]);
        }
    }
}

__global__ __launch_bounds__(256, 5) void grad_fused(
    const void* __restrict__ pos,
    const void* __restrict__ W1,
    const void* __restrict__ b1,
    void* __restrict__ out)
{
    __shared__ float S[HDIM][NB];   // 32 KiB -> 5 blocks/CU (LDS-limited)

    if (detect_bf(pos)) run_impl<true >(pos, W1, b1, out, S);
    else                run_impl<false>(pos, W1, b1, out, S);
}

extern "C" void kernel_launch(void* const* d_in, const int* in_sizes, int n_in,
                              void* d_out, int out_size, void* d_ws, size_t ws_size,
                              hipStream_t stream) {
    (void)d_ws; (void)ws_size; (void)in_sizes; (void)n_in; (void)out_size;
    const void* pos = d_in[0];  // [N,3]
    const void* W1  = d_in[1];  // [3,H]
    const void* b1  = d_in[2];  // [H]
    const void* W2  = d_in[3];  // [H,C]

    // Kernel 1: build B = W2 (x) W1 products (128 blocks x 256 threads).
    build_B<<<(HDIM * NTY * BPAD) / 256, 256, 0, stream>>>(pos, W1, W2);

    // Kernel 2: fused sech^2 + GEMM.
    int grid = (N_NODES + NB - 1) / NB;  // 1563 blocks
    grad_fused<<<grid, 256, 0, stream>>>(pos, W1, b1, d_out);
}

// Round 5
// 84.644 us; speedup vs baseline: 2.3752x; 2.3752x over previous
//
#include <hip/hip_runtime.h>
#include <hip/hip_bf16.h>

#define N_NODES 50000
#define HDIM    256
#define CDIM    32
#define JDIM    96     // C*3 outputs per node
#define NBLK    64     // nodes per block
#define KSTEPS  8      // 8 x 32 = 256 K

typedef __attribute__((ext_vector_type(8))) short short8v;  // 8 bf16 = 4 VGPR
typedef __attribute__((ext_vector_type(4))) float f32x4;

// B[h][j] = W1[j%3, h] * W2[h, j/3], stored in MFMA fragment order:
// element idx = ((ks*6 + jt)*64 + lane)*8 + je  ->  k = ks*32 + (lane>>4)*8 + je,
// col = jt*16 + (lane&15).  Split precision: Bh = bf16(B), Bl = bf16(B - Bh).
__device__ short  g_Bh[KSTEPS * 6 * 64 * 8];   // 48 KiB
__device__ short  g_Bl[KSTEPS * 6 * 64 * 8];   // 48 KiB
__device__ float4 g_Zc[HDIM];                  // {b1[h], W1[0,h], W1[1,h], W1[2,h]}

template<bool ISBF>
__device__ __forceinline__ float ldv(const void* __restrict__ p, int i) {
    if constexpr (ISBF) return __bfloat162float(((const __hip_bfloat16*)p)[i]);
    else                return ((const float*)p)[i];
}

// Runtime dtype detection (wave-uniform): bf16 ~N(0,1) has exponent in [100,140].
__device__ __forceinline__ bool detect_bf(const void* pos) {
    unsigned short uw = ((const unsigned short*)pos)[threadIdx.x & 63];
    int ef = (uw >> 7) & 0xFF;
    unsigned long long bal = __ballot(ef >= 100 && ef <= 140);
    return __popcll(bal) >= 56;
}

template<bool ISBF>
__device__ __forceinline__ void build_impl(const void* __restrict__ W1,
                                           const void* __restrict__ b1,
                                           const void* __restrict__ W2) {
    const int idx  = blockIdx.x * 256 + threadIdx.x;   // 0..24575
    const int je   = idx & 7;
    const int lane = (idx >> 3) & 63;
    const int f    = idx >> 9;                         // 0..47
    const int ks   = f / 6, jt = f % 6;
    const int h    = ks * 32 + (lane >> 4) * 8 + je;   // k index (= h)
    const int col  = jt * 16 + (lane & 15);            // j index
    float b = ldv<ISBF>(W1, (col % 3) * HDIM + h) * ldv<ISBF>(W2, h * CDIM + col / 3);
    __hip_bfloat16 hi = __float2bfloat16(b);
    float lo = b - __bfloat162float(hi);
    g_Bh[idx] = (short)__hip_bfloat16_raw(hi).x;
    g_Bl[idx] = (short)__hip_bfloat16_raw(__float2bfloat16(lo)).x;
    if (idx < HDIM) {
        g_Zc[idx] = make_float4(ldv<ISBF>(b1, idx),
                                ldv<ISBF>(W1, 0 * HDIM + idx),
                                ldv<ISBF>(W1, 1 * HDIM + idx),
                                ldv<ISBF>(W1, 2 * HDIM + idx));
    }
}

__global__ __launch_bounds__(256) void build_B(const void* __restrict__ pos,
                                               const void* __restrict__ W1,
                                               const void* __restrict__ b1,
                                               const void* __restrict__ W2) {
    if (detect_bf(pos)) build_impl<true >(W1, b1, W2);
    else                build_impl<false>(W1, b1, W2);
}

// Main kernel. Block = 256 thr = 4 waves, 64 nodes.
// Phase 1: S[n,h] = sech^2(z) computed once, stored to LDS as split bf16
//   SHL[0] = hi, SHL[1] = lo; row = node (512 B), XOR-swizzle bits 4-5 by (row&3).
// Phase 2: wave w: nodes [32*(w>>1), +32), j-half (w&1)*48. Per k-step:
//   4 ds_read_b128 (A hi/lo x 2 row-tiles, single vaddr + imm offsets),
//   6 global_load_dwordx4 (B frags, coalesced, L2-hot), 18 MFMA (3-term split).
// k-mapping consistency: A and B both stored with k = (lane>>4)*8 + je, so any
// true HW k-permutation cancels in the dot product.
template<bool ISBF>
__device__ __forceinline__ void run_impl(
    const void* __restrict__ pos,
    void* __restrict__ out,
    short* __restrict__ SHL)   // [2][64][256] bf16 = 65536 B
{
    const int tid  = threadIdx.x;
    const int lane = tid & 63;
    const int wv   = __builtin_amdgcn_readfirstlane(tid >> 6);  // uniform wave id

    // ---- phase 1: S -> LDS (this thread: node = lane, 64 h-values) ----
    {
        const int nl = lane;
        const int hg = wv;                       // 0..3, uniform -> g_Zc scalarizes
        const int n  = blockIdx.x * NBLK + nl;
        float p0 = 0.f, p1 = 0.f, p2 = 0.f;
        if (n < N_NODES) {
            p0 = ldv<ISBF>(pos, n * 3 + 0);
            p1 = ldv<ISBF>(pos, n * 3 + 1);
            p2 = ldv<ISBF>(pos, n * 3 + 2);
        }
        char* wb = (char*)SHL + nl * 512;
        const unsigned int swz = (unsigned)((nl & 3) << 4);
#pragma unroll 4
        for (int i = 0; i < 64; i += 4) {
            unsigned int ph[2], pl[2];
#pragma unroll
            for (int t = 0; t < 4; ++t) {
                const int h = hg * 64 + i + t;
                float4 zc = g_Zc[h];
                float z   = fmaf(p0, zc.y, fmaf(p1, zc.z, fmaf(p2, zc.w, zc.x)));
                // sech^2(z) = 4u/(1+u)^2, u = e^{-2|z|}: branch-free, no overflow
                float u   = __expf(-2.0f * fabsf(z));
                float inv = __builtin_amdgcn_rcpf(1.0f + u);
                float s   = 4.0f * u * inv * inv;
                __hip_bfloat16 hb = __float2bfloat16(s);
                unsigned int hr = __hip_bfloat16_raw(hb).x;
                float lf = s - __bfloat162float(hb);
                unsigned int lr = __hip_bfloat16_raw(__float2bfloat16(lf)).x;
                if (t & 1) { ph[t >> 1] |= hr << 16; pl[t >> 1] |= lr << 16; }
                else       { ph[t >> 1]  = hr;       pl[t >> 1]  = lr;       }
            }
            const unsigned int off = (unsigned)((hg * 128 + 2 * i)) ^ swz;
            *(uint2*)(wb + off)         = make_uint2(ph[0], ph[1]);   // hi
            *(uint2*)(wb + 32768 + off) = make_uint2(pl[0], pl[1]);   // lo
        }
    }
    __syncthreads();

    // ---- phase 2: MFMA GEMM ----
    const int m0 = (wv >> 1) * 32;     // wave's node-subtile base (0 or 32)
    const int jh = wv & 1;             // wave's j-half (0 -> j 0..47, 1 -> 48..95)
    const int arow = m0 + (lane & 15);
    const char* ab = (const char*)SHL + arow * 512
                   + (unsigned)((16 * (lane >> 4)) ^ ((arow & 3) << 4));
    const short8v* __restrict__ Bh = (const short8v*)g_Bh + jh * 192 + lane;
    const short8v* __restrict__ Bl = (const short8v*)g_Bl + jh * 192 + lane;

    f32x4 acc[2][3] = {};
#pragma unroll
    for (int ks = 0; ks < KSTEPS; ++ks) {
        short8v ah0 = *(const short8v*)(ab + ks * 64);                  // Shi, rows m0..+16
        short8v ah1 = *(const short8v*)(ab + 8192 + ks * 64);           // Shi, rows +16..+32
        short8v al0 = *(const short8v*)(ab + 32768 + ks * 64);          // Slo
        short8v al1 = *(const short8v*)(ab + 32768 + 8192 + ks * 64);
#pragma unroll
        for (int jt = 0; jt < 3; ++jt) {
            short8v bh = Bh[ks * 384 + jt * 64];
            short8v bl = Bl[ks * 384 + jt * 64];
            acc[0][jt] = __builtin_amdgcn_mfma_f32_16x16x32_bf16(ah0, bh, acc[0][jt], 0, 0, 0);
            acc[1][jt] = __builtin_amdgcn_mfma_f32_16x16x32_bf16(ah1, bh, acc[1][jt], 0, 0, 0);
            acc[0][jt] = __builtin_amdgcn_mfma_f32_16x16x32_bf16(ah0, bl, acc[0][jt], 0, 0, 0);
            acc[1][jt] = __builtin_amdgcn_mfma_f32_16x16x32_bf16(ah1, bl, acc[1][jt], 0, 0, 0);
            acc[0][jt] = __builtin_amdgcn_mfma_f32_16x16x32_bf16(al0, bh, acc[0][jt], 0, 0, 0);
            acc[1][jt] = __builtin_amdgcn_mfma_f32_16x16x32_bf16(al1, bh, acc[1][jt], 0, 0, 0);
        }
    }

    // ---- store: C/D layout col = lane&15, row = (lane>>4)*4 + reg ----
    const int colb = jh * 48 + (lane & 15);
    const int rowb = blockIdx.x * NBLK + m0 + (lane >> 4) * 4;
#pragma unroll
    for (int mt = 0; mt < 2; ++mt) {
#pragma unroll
        for (int r = 0; r < 4; ++r) {
            const int n = rowb + mt * 16 + r;
            if (n >= N_NODES) continue;
#pragma unroll
            for (int jt = 0; jt < 3; ++jt) {
                if constexpr (ISBF) {
                    ((unsigned short*)out)[(size_t)n * JDIM + colb + jt * 16] =
                        __hip_bfloat16_raw(__float2bfloat16(acc[mt][jt][r])).x;
                } else {
                    ((float*)out)[(size_t)n * JDIM + colb + jt * 16] = acc[mt][jt][r];
                }
            }
        }
    }
}

__global__ __launch_bounds__(256, 2) void grad_fused(
    const void* __restrict__ pos,
    void* __restrict__ out)
{
    __shared__ short SHL[2 * 64 * 256];   // 64 KiB exactly -> 2 blocks/CU

    if (detect_bf(pos)) run_impl<true >(pos, out, SHL);
    else                run_impl<false>(pos, out, SHL);
}

extern "C" void kernel_launch(void* const* d_in, const int* in_sizes, int n_in,
                              void* d_out, int out_size, void* d_ws, size_t ws_size,
                              hipStream_t stream) {
    (void)d_ws; (void)ws_size; (void)in_sizes; (void)n_in; (void)out_size;
    const void* pos = d_in[0];  // [N,3]
    const void* W1  = d_in[1];  // [3,H]
    const void* b1  = d_in[2];  // [H]
    const void* W2  = d_in[3];  // [H,C]

    // Kernel 1: build split-bf16 B fragments + packed z-coefficients.
    build_B<<<(KSTEPS * 6 * 64 * 8) / 256, 256, 0, stream>>>(pos, W1, b1, W2);

    // Kernel 2: fused sech^2 + MFMA GEMM.
    int grid = (N_NODES + NBLK - 1) / NBLK;  // 782 blocks
    grad_fused<<<grid, 256, 0, stream>>>(pos, d_out);
}

// Round 6
// 82.795 us; speedup vs baseline: 2.4282x; 1.0223x over previous
//
#include <hip/hip_runtime.h>
#include <hip/hip_bf16.h>

#define N_NODES 50000
#define HDIM    256
#define CDIM    32
#define JDIM    96     // C*3 outputs per node
#define NBLK    64     // nodes per block
#define KSTEPS  8      // 8 x 32 = 256 K

typedef __attribute__((ext_vector_type(8))) short short8v;  // 8 bf16 = 4 VGPR
typedef __attribute__((ext_vector_type(4))) float f32x4;

// B[h][j] = W1[j%3, h] * W2[h, j/3], stored in MFMA fragment order:
// element idx = ((ks*6 + jt)*64 + lane)*8 + je  ->  k = ks*32 + (lane>>4)*8 + je,
// col = jt*16 + (lane&15).  Split precision: Bh = bf16(B), Bl = bf16(B - Bh).
__device__ short  g_Bh[KSTEPS * 6 * 64 * 8];   // 48 KiB
__device__ short  g_Bl[KSTEPS * 6 * 64 * 8];   // 48 KiB
__device__ float4 g_Zc[HDIM];                  // {b1[h], W1[0,h], W1[1,h], W1[2,h]}

template<bool ISBF>
__device__ __forceinline__ float ldv(const void* __restrict__ p, int i) {
    if constexpr (ISBF) return __bfloat162float(((const __hip_bfloat16*)p)[i]);
    else                return ((const float*)p)[i];
}

// Runtime dtype detection (wave-uniform): bf16 ~N(0,1) has exponent in [100,140].
__device__ __forceinline__ bool detect_bf(const void* pos) {
    unsigned short uw = ((const unsigned short*)pos)[threadIdx.x & 63];
    int ef = (uw >> 7) & 0xFF;
    unsigned long long bal = __ballot(ef >= 100 && ef <= 140);
    return __popcll(bal) >= 56;
}

template<bool ISBF>
__device__ __forceinline__ void build_impl(const void* __restrict__ W1,
                                           const void* __restrict__ b1,
                                           const void* __restrict__ W2) {
    const int idx  = blockIdx.x * 256 + threadIdx.x;   // 0..24575
    const int je   = idx & 7;
    const int lane = (idx >> 3) & 63;
    const int f    = idx >> 9;                         // 0..47
    const int ks   = f / 6, jt = f % 6;
    const int h    = ks * 32 + (lane >> 4) * 8 + je;   // k index (= h)
    const int col  = jt * 16 + (lane & 15);            // j index
    float b = ldv<ISBF>(W1, (col % 3) * HDIM + h) * ldv<ISBF>(W2, h * CDIM + col / 3);
    __hip_bfloat16 hi = __float2bfloat16(b);
    float lo = b - __bfloat162float(hi);
    g_Bh[idx] = (short)__hip_bfloat16_raw(hi).x;
    g_Bl[idx] = (short)__hip_bfloat16_raw(__float2bfloat16(lo)).x;
    if (idx < HDIM) {
        g_Zc[idx] = make_float4(ldv<ISBF>(b1, idx),
                                ldv<ISBF>(W1, 0 * HDIM + idx),
                                ldv<ISBF>(W1, 1 * HDIM + idx),
                                ldv<ISBF>(W1, 2 * HDIM + idx));
    }
}

__global__ __launch_bounds__(256) void build_B(const void* __restrict__ pos,
                                               const void* __restrict__ W1,
                                               const void* __restrict__ b1,
                                               const void* __restrict__ W2) {
    if (detect_bf(pos)) build_impl<true >(W1, b1, W2);
    else                build_impl<false>(W1, b1, W2);
}

// Main kernel. Block = 256 thr = 4 waves, 64 nodes.
// Phase 1: S = sech^2(z) once per (n,h); split to bf16 hi/lo by TRUNCATION
//   (hi = s & 0xFFFF0000, lo = s - hi; hi+lo == s up to 2^-17) and packed
//   with v_perm_b32. LDS row = node (512 B), byte offsets XOR-swizzled by
//   ((row&7)<<4) -> phase-2 ds_read_b128 spreads over 8 bank slots (~2-way).
// Phase 2: wave w: nodes [32*(w>>1), +32), j-half (w&1)*48. Per k-step:
//   4 ds_read_b128 (A hi/lo x 2 row-tiles) + 6 global dwordx4 (B, L2-hot)
//   + 18 MFMA in TERM-MAJOR order (acc reuse distance 6 >= MFMA latency).
// Swizzle bit 6 collides with the ks*64 immediate, so it is folded into two
// base pointers: even ks uses base+sw6, odd ks uses base+(64-sw6).
template<bool ISBF>
__device__ __forceinline__ void run_impl(
    const void* __restrict__ pos,
    void* __restrict__ out,
    short* __restrict__ SHL)   // [2][64][256] bf16 = 65536 B
{
    const int tid  = threadIdx.x;
    const int lane = tid & 63;
    const int wv   = __builtin_amdgcn_readfirstlane(tid >> 6);  // uniform wave id

    // ---- phase 1: S -> LDS (this thread: node = lane, 64 h-values) ----
    {
        const int nl = lane;
        const int hg = wv;                       // 0..3, uniform -> g_Zc scalarizes
        const int n  = blockIdx.x * NBLK + nl;
        float p0 = 0.f, p1 = 0.f, p2 = 0.f;
        if (n < N_NODES) {
            p0 = ldv<ISBF>(pos, n * 3 + 0);
            p1 = ldv<ISBF>(pos, n * 3 + 1);
            p2 = ldv<ISBF>(pos, n * 3 + 2);
        }
        char* wb = (char*)SHL + nl * 512;
        const unsigned int swz = (unsigned)((nl & 7) << 4);
#pragma unroll 4
        for (int i = 0; i < 64; i += 4) {
            unsigned int hb[4], lb[4];
#pragma unroll
            for (int t = 0; t < 4; ++t) {
                const int h = hg * 64 + i + t;
                float4 zc = g_Zc[h];
                float z   = fmaf(p0, zc.y, fmaf(p1, zc.z, fmaf(p2, zc.w, zc.x)));
                // sech^2(z) = 4u/(1+u)^2, u = e^{-2|z|}: branch-free, no overflow
                float u   = __expf(-2.0f * fabsf(z));
                float inv = __builtin_amdgcn_rcpf(1.0f + u);
                float s   = 4.0f * u * inv * inv;
                hb[t] = __float_as_uint(s) & 0xffff0000u;            // bf16-trunc hi
                lb[t] = __float_as_uint(s - __uint_as_float(hb[t])); // exact residual
            }
            // pack high-16 of pairs: dst = {x1[31:16], x0[31:16]}
            unsigned int ph0 = __builtin_amdgcn_perm(hb[1], hb[0], 0x07060302u);
            unsigned int ph1 = __builtin_amdgcn_perm(hb[3], hb[2], 0x07060302u);
            unsigned int pl0 = __builtin_amdgcn_perm(lb[1], lb[0], 0x07060302u);
            unsigned int pl1 = __builtin_amdgcn_perm(lb[3], lb[2], 0x07060302u);
            const unsigned int off = (unsigned)((hg * 128 + 2 * i)) ^ swz;
            *(uint2*)(wb + off)         = make_uint2(ph0, ph1);   // hi
            *(uint2*)(wb + 32768 + off) = make_uint2(pl0, pl1);   // lo
        }
    }
    __syncthreads();

    // ---- phase 2: MFMA GEMM ----
    const int m0 = (wv >> 1) * 32;     // wave's node-subtile base (0 or 32)
    const int jh = wv & 1;             // wave's j-half (0 -> j 0..47, 1 -> 48..95)
    const int arow = m0 + (lane & 15);
    const unsigned int sw   = (unsigned)((arow & 7) << 4);   // bits 4-6
    const unsigned int sw45 = sw & 0x30u;
    const unsigned int sw6  = sw & 0x40u;
    const char* base = (const char*)SHL + arow * 512
                     + (unsigned)(((lane >> 4) * 16) ^ sw45);
    const char* abE = base + sw6;          // even ks: (ks*64)^sw6 = ks*64 + sw6
    const char* abO = base + (64 - sw6);   // odd  ks: (ks*64)^sw6 = (ks-1)*64 + 64 - sw6

    const short8v* __restrict__ Bh = (const short8v*)g_Bh + jh * 192 + lane;
    const short8v* __restrict__ Bl = (const short8v*)g_Bl + jh * 192 + lane;

    f32x4 a00 = {}, a01 = {}, a02 = {}, a10 = {}, a11 = {}, a12 = {};
#pragma unroll
    for (int ks = 0; ks < KSTEPS; ++ks) {
        const char* ap = ((ks & 1) ? abO : abE) + (ks & ~1) * 64;
        short8v ah0 = *(const short8v*)(ap);                    // Shi rows m0..+16
        short8v ah1 = *(const short8v*)(ap + 8192);             // Shi rows +16..+32
        short8v al0 = *(const short8v*)(ap + 32768);            // Slo
        short8v al1 = *(const short8v*)(ap + 32768 + 8192);
        short8v bh0 = Bh[ks * 384 +   0];
        short8v bh1 = Bh[ks * 384 +  64];
        short8v bh2 = Bh[ks * 384 + 128];
        short8v bl0 = Bl[ks * 384 +   0];
        short8v bl1 = Bl[ks * 384 +  64];
        short8v bl2 = Bl[ks * 384 + 128];
        // term 1: Shi*Bhi
        a00 = __builtin_amdgcn_mfma_f32_16x16x32_bf16(ah0, bh0, a00, 0, 0, 0);
        a10 = __builtin_amdgcn_mfma_f32_16x16x32_bf16(ah1, bh0, a10, 0, 0, 0);
        a01 = __builtin_amdgcn_mfma_f32_16x16x32_bf16(ah0, bh1, a01, 0, 0, 0);
        a11 = __builtin_amdgcn_mfma_f32_16x16x32_bf16(ah1, bh1, a11, 0, 0, 0);
        a02 = __builtin_amdgcn_mfma_f32_16x16x32_bf16(ah0, bh2, a02, 0, 0, 0);
        a12 = __builtin_amdgcn_mfma_f32_16x16x32_bf16(ah1, bh2, a12, 0, 0, 0);
        // term 2: Shi*Blo
        a00 = __builtin_amdgcn_mfma_f32_16x16x32_bf16(ah0, bl0, a00, 0, 0, 0);
        a10 = __builtin_amdgcn_mfma_f32_16x16x32_bf16(ah1, bl0, a10, 0, 0, 0);
        a01 = __builtin_amdgcn_mfma_f32_16x16x32_bf16(ah0, bl1, a01, 0, 0, 0);
        a11 = __builtin_amdgcn_mfma_f32_16x16x32_bf16(ah1, bl1, a11, 0, 0, 0);
        a02 = __builtin_amdgcn_mfma_f32_16x16x32_bf16(ah0, bl2, a02, 0, 0, 0);
        a12 = __builtin_amdgcn_mfma_f32_16x16x32_bf16(ah1, bl2, a12, 0, 0, 0);
        // term 3: Slo*Bhi
        a00 = __builtin_amdgcn_mfma_f32_16x16x32_bf16(al0, bh0, a00, 0, 0, 0);
        a10 = __builtin_amdgcn_mfma_f32_16x16x32_bf16(al1, bh0, a10, 0, 0, 0);
        a01 = __builtin_amdgcn_mfma_f32_16x16x32_bf16(al0, bh1, a01, 0, 0, 0);
        a11 = __builtin_amdgcn_mfma_f32_16x16x32_bf16(al1, bh1, a11, 0, 0, 0);
        a02 = __builtin_amdgcn_mfma_f32_16x16x32_bf16(al0, bh2, a02, 0, 0, 0);
        a12 = __builtin_amdgcn_mfma_f32_16x16x32_bf16(al1, bh2, a12, 0, 0, 0);
    }

    // ---- store: C/D layout col = lane&15, row = (lane>>4)*4 + reg ----
    const int colb = jh * 48 + (lane & 15);
    const int rowb = blockIdx.x * NBLK + m0 + (lane >> 4) * 4;
    f32x4 accs[2][3] = {{a00, a01, a02}, {a10, a11, a12}};
#pragma unroll
    for (int mt = 0; mt < 2; ++mt) {
#pragma unroll
        for (int r = 0; r < 4; ++r) {
            const int n = rowb + mt * 16 + r;
            if (n >= N_NODES) continue;
#pragma unroll
            for (int jt = 0; jt < 3; ++jt) {
                if constexpr (ISBF) {
                    ((unsigned short*)out)[(size_t)n * JDIM + colb + jt * 16] =
                        __hip_bfloat16_raw(__float2bfloat16(accs[mt][jt][r])).x;
                } else {
                    ((float*)out)[(size_t)n * JDIM + colb + jt * 16] = accs[mt][jt][r];
                }
            }
        }
    }
}

__global__ __launch_bounds__(256, 2) void grad_fused(
    const void* __restrict__ pos,
    void* __restrict__ out)
{
    __shared__ short SHL[2 * 64 * 256];   // 64 KiB exactly -> 2 blocks/CU

    if (detect_bf(pos)) run_impl<true >(pos, out, SHL);
    else                run_impl<false>(pos, out, SHL);
}

extern "C" void kernel_launch(void* const* d_in, const int* in_sizes, int n_in,
                              void* d_out, int out_size, void* d_ws, size_t ws_size,
                              hipStream_t stream) {
    (void)d_ws; (void)ws_size; (void)in_sizes; (void)n_in; (void)out_size;
    const void* pos = d_in[0];  // [N,3]
    const void* W1  = d_in[1];  // [3,H]
    const void* b1  = d_in[2];  // [H]
    const void* W2  = d_in[3];  // [H,C]

    // Kernel 1: build split-bf16 B fragments + packed z-coefficients.
    build_B<<<(KSTEPS * 6 * 64 * 8) / 256, 256, 0, stream>>>(pos, W1, b1, W2);

    // Kernel 2: fused sech^2 + MFMA GEMM.
    int grid = (N_NODES + NBLK - 1) / NBLK;  // 782 blocks
    grad_fused<<<grid, 256, 0, stream>>>(pos, d_out);
}